// Round 1
// baseline (462.414 us; speedup 1.0000x reference)
//
#include <hip/hip_runtime.h>
#include <hip/hip_bf16.h>
#include <math.h>

#define BATCH 32
#define IMG 256
#define NCP 9

__device__ __constant__ float d_cpx[9] = {-1.f,0.f,1.f,-1.f,0.f,1.f,-1.f,0.f,1.f};
__device__ __constant__ float d_cpy[9] = {-1.f,-1.f,-1.f,0.f,0.f,0.f,1.f,1.f,1.f};

// ---------------- conv1 (1->32, 3x3 SAME) + maxpool2 + relu ----------------
// grid: B * 8 * 8 tiles, block 256. tile = 16x16 post-pool outputs.
__global__ __launch_bounds__(256) void k_conv1(const float* __restrict__ x,
        const float* __restrict__ w, const float* __restrict__ bias,
        float* __restrict__ f1) {
    int blk = blockIdx.x;
    int tj = blk & 7, ti = (blk >> 3) & 7, b = blk >> 6;
    __shared__ float tile[34 * 34];
    __shared__ float wl[32 * 9];
    __shared__ float bl[32];
    int tid = threadIdx.x;
    for (int i = tid; i < 32 * 9; i += 256) wl[i] = w[i];
    if (tid < 32) bl[tid] = bias[tid];
    const float* xb = x + (size_t)b * IMG * IMG;
    int oy0 = ti * 32 - 1, ox0 = tj * 32 - 1;   // input-space tile origin
    for (int i = tid; i < 34 * 34; i += 256) {
        int yy = i / 34, xx = i % 34;
        int r = oy0 + yy, c = ox0 + xx;
        float v = 0.f;
        if (r >= 0 && r < IMG && c >= 0 && c < IMG) v = xb[r * IMG + c];
        tile[i] = v;
    }
    __syncthreads();
    int oy = tid >> 4, ox = tid & 15;
    float p[16];
    #pragma unroll
    for (int yy = 0; yy < 4; ++yy)
        #pragma unroll
        for (int xx = 0; xx < 4; ++xx)
            p[yy * 4 + xx] = tile[(2 * oy + yy) * 34 + (2 * ox + xx)];
    int gy = ti * 16 + oy, gx = tj * 16 + ox;
    float* f1b = f1 + (size_t)b * 32 * 128 * 128;
    for (int oc = 0; oc < 32; ++oc) {
        float ww[9];
        #pragma unroll
        for (int k = 0; k < 9; ++k) ww[k] = wl[oc * 9 + k];
        float m = -INFINITY;
        #pragma unroll
        for (int dy = 0; dy < 2; ++dy)
            #pragma unroll
            for (int dx = 0; dx < 2; ++dx) {
                float s = 0.f;
                #pragma unroll
                for (int ky = 0; ky < 3; ++ky)
                    #pragma unroll
                    for (int kx = 0; kx < 3; ++kx)
                        s = fmaf(p[(dy + ky) * 4 + dx + kx], ww[ky * 3 + kx], s);
                m = fmaxf(m, s);
            }
        f1b[oc * 128 * 128 + gy * 128 + gx] = fmaxf(m + bl[oc], 0.f);
    }
}

// ------- conv2 (32->64, 3x3 SAME) + maxpool2 + relu + fused 16x16 avgpool ----
// grid: B * 8 ocgroups * 16 tiles, block 256. tile = 16x16 post-pool = one
// avgpool block -> writes feat directly, f2 never materialized.
__global__ __launch_bounds__(256) void k_conv2(const float* __restrict__ f1,
        const float* __restrict__ w, const float* __restrict__ bias,
        float* __restrict__ feat) {
    int blk = blockIdx.x;
    int tile_id = blk & 15, ocg = (blk >> 4) & 7, b = blk >> 7;
    int tj = tile_id & 3, ti = tile_id >> 2;
    __shared__ float tile[34 * 34];
    __shared__ float wl[8 * 32 * 9];
    __shared__ float red[8 * 4];
    int tid = threadIdx.x;
    for (int i = tid; i < 2304; i += 256) wl[i] = w[ocg * 2304 + i];
    float acc[8][4];
    #pragma unroll
    for (int o = 0; o < 8; ++o)
        #pragma unroll
        for (int q = 0; q < 4; ++q) acc[o][q] = 0.f;
    int oy = tid >> 4, ox = tid & 15;
    int oy0 = ti * 32 - 1, ox0 = tj * 32 - 1;
    const float* f1b = f1 + (size_t)b * 32 * 128 * 128;
    for (int ic = 0; ic < 32; ++ic) {
        __syncthreads();
        const float* src = f1b + ic * 128 * 128;
        for (int i = tid; i < 34 * 34; i += 256) {
            int yy = i / 34, xx = i % 34;
            int r = oy0 + yy, c = ox0 + xx;
            float v = 0.f;
            if (r >= 0 && r < 128 && c >= 0 && c < 128) v = src[r * 128 + c];
            tile[i] = v;
        }
        __syncthreads();
        float p[16];
        #pragma unroll
        for (int yy = 0; yy < 4; ++yy)
            #pragma unroll
            for (int xx = 0; xx < 4; ++xx)
                p[yy * 4 + xx] = tile[(2 * oy + yy) * 34 + (2 * ox + xx)];
        #pragma unroll
        for (int o = 0; o < 8; ++o) {
            const float* wp = &wl[(o * 32 + ic) * 9];
            float ww[9];
            #pragma unroll
            for (int k = 0; k < 9; ++k) ww[k] = wp[k];
            #pragma unroll
            for (int dy = 0; dy < 2; ++dy)
                #pragma unroll
                for (int dx = 0; dx < 2; ++dx) {
                    float s = acc[o][dy * 2 + dx];
                    #pragma unroll
                    for (int ky = 0; ky < 3; ++ky)
                        #pragma unroll
                        for (int kx = 0; kx < 3; ++kx)
                            s = fmaf(p[(dy + ky) * 4 + dx + kx], ww[ky * 3 + kx], s);
                    acc[o][dy * 2 + dx] = s;
                }
        }
    }
    int lane = tid & 63, wave = tid >> 6;
    float* featb = feat + (size_t)b * 1024;
    #pragma unroll
    for (int o = 0; o < 8; ++o) {
        float m = fmaxf(fmaxf(acc[o][0], acc[o][1]), fmaxf(acc[o][2], acc[o][3]));
        float v = fmaxf(m + bias[ocg * 8 + o], 0.f);
        for (int off = 32; off; off >>= 1) v += __shfl_down(v, off);
        if (lane == 0) red[o * 4 + wave] = v;
    }
    __syncthreads();
    if (tid < 8) {
        float s = red[tid * 4] + red[tid * 4 + 1] + red[tid * 4 + 2] + red[tid * 4 + 3];
        featb[(ocg * 8 + tid) * 16 + ti * 4 + tj] = s * (1.0f / 256.0f);
    }
}

// ---------------- fc1 (1024->256) + relu: one wave per output ----------------
__global__ __launch_bounds__(256) void k_fc1(const float* __restrict__ feat,
        const float* __restrict__ w, const float* __restrict__ bias,
        float* __restrict__ h) {
    int wave = threadIdx.x >> 6, lane = threadIdx.x & 63;
    int o = blockIdx.x * 4 + wave;           // o in [0, 8192)
    int b = o >> 8, j = o & 255;
    const float* wr = w + (size_t)j * 1024;
    const float* fb = feat + (size_t)b * 1024;
    float s = 0.f;
    #pragma unroll
    for (int k = lane; k < 1024; k += 64) s = fmaf(wr[k], fb[k], s);
    for (int off = 32; off; off >>= 1) s += __shfl_down(s, off);
    if (lane == 0) h[o] = fmaxf(s + bias[j], 0.f);
}

// ---------------- build and invert the constant 12x12 TPS matrix ----------------
__global__ void k_linv(float* __restrict__ linv) {
    __shared__ float M[12][24];
    if (threadIdx.x == 0) {
        const float cx[9] = {-1,0,1,-1,0,1,-1,0,1};
        const float cy[9] = {-1,-1,-1,0,0,0,1,1,1};
        for (int i = 0; i < 12; ++i)
            for (int j = 0; j < 24; ++j) M[i][j] = 0.f;
        for (int i = 0; i < 9; ++i) {
            for (int j = 0; j < 9; ++j) {
                float dx = cx[i] - cx[j], dy = cy[i] - cy[j];
                float r2 = dx * dx + dy * dy;
                M[i][j] = (r2 > 0.f) ? r2 * logf(r2) : 0.f;
            }
            M[i][9] = 1.f; M[i][10] = cx[i]; M[i][11] = cy[i];
            M[9][i] = 1.f; M[10][i] = cx[i]; M[11][i] = cy[i];
        }
        for (int i = 0; i < 12; ++i) M[i][12 + i] = 1.f;
        for (int c = 0; c < 12; ++c) {
            int p = c;
            for (int r = c + 1; r < 12; ++r)
                if (fabsf(M[r][c]) > fabsf(M[p][c])) p = r;
            if (p != c)
                for (int j = 0; j < 24; ++j) { float t = M[c][j]; M[c][j] = M[p][j]; M[p][j] = t; }
            float inv = 1.f / M[c][c];
            for (int j = 0; j < 24; ++j) M[c][j] *= inv;
            for (int r = 0; r < 12; ++r) if (r != c) {
                float f = M[r][c];
                for (int j = 0; j < 24; ++j) M[r][j] -= f * M[c][j];
            }
        }
        for (int i = 0; i < 12; ++i)
            for (int j = 0; j < 12; ++j) linv[i * 12 + j] = M[i][12 + j];
    }
}

// -------- fc2 (256->18) + Y build + Wfull = Linv @ Y  (one block per batch) ----
__global__ __launch_bounds__(64) void k_head(const float* __restrict__ h,
        const float* __restrict__ w2, const float* __restrict__ b2,
        const float* __restrict__ linv, float* __restrict__ wfull) {
    int b = blockIdx.x;
    int t = threadIdx.x;
    __shared__ float Y[12][2];
    __shared__ float L[144];
    const float* hb = h + (size_t)b * 256;
    for (int i = t; i < 144; i += 64) L[i] = linv[i];
    if (t < 18) {
        const float* wr = w2 + (size_t)t * 256;
        float s = 0.f;
        for (int k = 0; k < 256; ++k) s = fmaf(wr[k], hb[k], s);
        s += b2[t];
        int kk = t >> 1, d = t & 1;
        float cp = (d == 0) ? d_cpx[kk] : d_cpy[kk];
        Y[kk][d] = cp + s;
    }
    if (t >= 18 && t < 24) Y[9 + ((t - 18) >> 1)][(t - 18) & 1] = 0.f;
    __syncthreads();
    if (t < 24) {
        int i = t >> 1, d = t & 1;
        float s = 0.f;
        #pragma unroll
        for (int k = 0; k < 12; ++k) s = fmaf(L[i * 12 + k], Y[k][d], s);
        wfull[b * 24 + i * 2 + d] = s;
    }
}

// -------- fused warp-grid (TPS eval) + bilinear grid_sample (zero pad) --------
// grid: B*256 blocks, one image row per block.
__global__ __launch_bounds__(256) void k_sample(const float* __restrict__ x,
        const float* __restrict__ wfull, float* __restrict__ out) {
    int b = blockIdx.x >> 8;
    int py = blockIdx.x & 255;
    int px = threadIdx.x;
    __shared__ float Wf[24];
    if (threadIdx.x < 24) Wf[threadIdx.x] = wfull[b * 24 + threadIdx.x];
    __syncthreads();
    float gx = px * (2.0f / 255.0f) - 1.0f;
    float gy = py * (2.0f / 255.0f) - 1.0f;
    float sx = Wf[18] + Wf[20] * gx + Wf[22] * gy;   // affine rows 9..11
    float sy = Wf[19] + Wf[21] * gx + Wf[23] * gy;
    #pragma unroll
    for (int k = 0; k < 9; ++k) {
        float dx = gx - d_cpx[k], dy = gy - d_cpy[k];
        float r2 = dx * dx + dy * dy;
        float u = (r2 > 0.f) ? r2 * logf(r2) : 0.f;
        sx = fmaf(u, Wf[k * 2 + 0], sx);
        sy = fmaf(u, Wf[k * 2 + 1], sy);
    }
    float xp = (sx + 1.0f) * 0.5f * 255.0f;
    float yp = (sy + 1.0f) * 0.5f * 255.0f;
    float x0f = floorf(xp), y0f = floorf(yp);
    float wx = xp - x0f, wy = yp - y0f;
    int x0 = (int)x0f, y0 = (int)y0f;
    const float* xb = x + (size_t)b * IMG * IMG;
    float v00, v10, v01, v11;
    {
        int ix, iy; bool valid; int ixc, iyc;
        ix = x0;     iy = y0;
        valid = (ix >= 0) && (ix < IMG) && (iy >= 0) && (iy < IMG);
        ixc = min(max(ix, 0), IMG - 1); iyc = min(max(iy, 0), IMG - 1);
        v00 = valid ? xb[iyc * IMG + ixc] : 0.f;
        ix = x0 + 1; iy = y0;
        valid = (ix >= 0) && (ix < IMG) && (iy >= 0) && (iy < IMG);
        ixc = min(max(ix, 0), IMG - 1); iyc = min(max(iy, 0), IMG - 1);
        v10 = valid ? xb[iyc * IMG + ixc] : 0.f;
        ix = x0;     iy = y0 + 1;
        valid = (ix >= 0) && (ix < IMG) && (iy >= 0) && (iy < IMG);
        ixc = min(max(ix, 0), IMG - 1); iyc = min(max(iy, 0), IMG - 1);
        v01 = valid ? xb[iyc * IMG + ixc] : 0.f;
        ix = x0 + 1; iy = y0 + 1;
        valid = (ix >= 0) && (ix < IMG) && (iy >= 0) && (iy < IMG);
        ixc = min(max(ix, 0), IMG - 1); iyc = min(max(iy, 0), IMG - 1);
        v11 = valid ? xb[iyc * IMG + ixc] : 0.f;
    }
    float r = v00 * (1.f - wx) * (1.f - wy) + v10 * wx * (1.f - wy)
            + v01 * (1.f - wx) * wy        + v11 * wx * wy;
    out[(size_t)b * IMG * IMG + py * IMG + px] = r;
}

extern "C" void kernel_launch(void* const* d_in, const int* in_sizes, int n_in,
                              void* d_out, int out_size, void* d_ws, size_t ws_size,
                              hipStream_t stream) {
    const float* x   = (const float*)d_in[0];
    const float* c1w = (const float*)d_in[1];
    const float* c1b = (const float*)d_in[2];
    const float* c2w = (const float*)d_in[3];
    const float* c2b = (const float*)d_in[4];
    const float* w1  = (const float*)d_in[5];
    const float* b1  = (const float*)d_in[6];
    const float* w2  = (const float*)d_in[7];
    const float* b2  = (const float*)d_in[8];
    float* out = (float*)d_out;

    float* ws    = (float*)d_ws;
    float* f1    = ws;                       // 32*32*128*128 = 16777216 floats
    float* feat  = f1 + 16777216;            // 32*1024
    float* hbuf  = feat + 32768;             // 32*256
    float* wfull = hbuf + 8192;              // 32*24
    float* linv  = wfull + 768;              // 144

    k_linv<<<1, 64, 0, stream>>>(linv);
    k_conv1<<<BATCH * 64, 256, 0, stream>>>(x, c1w, c1b, f1);
    k_conv2<<<BATCH * 8 * 16, 256, 0, stream>>>(f1, c2w, c2b, feat);
    k_fc1<<<2048, 256, 0, stream>>>(feat, w1, b1, hbuf);
    k_head<<<BATCH, 64, 0, stream>>>(hbuf, w2, b2, linv, wfull);
    k_sample<<<BATCH * 256, 256, 0, stream>>>(x, wfull, out);
}

// Round 2
// 139.105 us; speedup vs baseline: 3.3242x; 3.3242x over previous
//
#include <hip/hip_runtime.h>
#include <hip/hip_bf16.h>
#include <math.h>

#define BATCH 32
#define IMG 256
#define NCP 9
#define F1P 130              // padded spatial dim of f1 (128 + 2 border)

typedef __attribute__((ext_vector_type(8))) short bf16x8;
typedef __attribute__((ext_vector_type(4))) float f32x4;
typedef __attribute__((ext_vector_type(4))) unsigned int uint4v;

__device__ __constant__ float d_cpx[9] = {-1.f,0.f,1.f,-1.f,0.f,1.f,-1.f,0.f,1.f};
__device__ __constant__ float d_cpy[9] = {-1.f,-1.f,-1.f,0.f,0.f,0.f,1.f,1.f,1.f};

__device__ inline unsigned int pack2bf(float a, float b) {
    __hip_bfloat16 ha = __float2bfloat16(a), hb = __float2bfloat16(b);
    unsigned short ua = *(unsigned short*)&ha, ub = *(unsigned short*)&hb;
    return ((unsigned int)ub << 16) | ua;
}

// ---------------- conv1 (1->32) + maxpool2 + relu -> f1 [b][y+1][x+1][ic] bf16 ----
__global__ __launch_bounds__(256) void k_conv1(const float* __restrict__ x,
        const float* __restrict__ w, const float* __restrict__ bias,
        __hip_bfloat16* __restrict__ f1) {
    int blk = blockIdx.x;
    int tj = blk & 7, ti = (blk >> 3) & 7, b = blk >> 6;
    __shared__ float tile[34 * 34];
    __shared__ float wl[32 * 9];
    __shared__ float bl[32];
    int tid = threadIdx.x;
    for (int i = tid; i < 32 * 9; i += 256) wl[i] = w[i];
    if (tid < 32) bl[tid] = bias[tid];
    const float* xb = x + (size_t)b * IMG * IMG;
    int oy0 = ti * 32 - 1, ox0 = tj * 32 - 1;
    for (int i = tid; i < 34 * 34; i += 256) {
        int yy = i / 34, xx = i % 34;
        int r = oy0 + yy, c = ox0 + xx;
        float v = 0.f;
        if (r >= 0 && r < IMG && c >= 0 && c < IMG) v = xb[r * IMG + c];
        tile[i] = v;
    }
    __syncthreads();
    int oy = tid >> 4, ox = tid & 15;
    float p[16];
    #pragma unroll
    for (int yy = 0; yy < 4; ++yy)
        #pragma unroll
        for (int xx = 0; xx < 4; ++xx)
            p[yy * 4 + xx] = tile[(2 * oy + yy) * 34 + (2 * ox + xx)];
    int gy = ti * 16 + oy, gx = tj * 16 + ox;
    unsigned int u[16];
    #pragma unroll
    for (int oc2 = 0; oc2 < 16; ++oc2) {
        float vv[2];
        #pragma unroll
        for (int h = 0; h < 2; ++h) {
            int oc = oc2 * 2 + h;
            float ww[9];
            #pragma unroll
            for (int k = 0; k < 9; ++k) ww[k] = wl[oc * 9 + k];
            float m = -INFINITY;
            #pragma unroll
            for (int dy = 0; dy < 2; ++dy)
                #pragma unroll
                for (int dx = 0; dx < 2; ++dx) {
                    float s = 0.f;
                    #pragma unroll
                    for (int ky = 0; ky < 3; ++ky)
                        #pragma unroll
                        for (int kx = 0; kx < 3; ++kx)
                            s = fmaf(p[(dy + ky) * 4 + dx + kx], ww[ky * 3 + kx], s);
                    m = fmaxf(m, s);
                }
            vv[h] = fmaxf(m + bl[oc], 0.f);
        }
        u[oc2] = pack2bf(vv[0], vv[1]);
    }
    size_t eo = (((size_t)b * F1P + (gy + 1)) * F1P + (gx + 1)) * 32;  // elements
    uint4v* dst = (uint4v*)((char*)f1 + eo * 2);
    #pragma unroll
    for (int q = 0; q < 4; ++q) {
        uint4v vq = { u[q*4+0], u[q*4+1], u[q*4+2], u[q*4+3] };
        dst[q] = vq;
    }
}

// ---------------- zero the 1-px border of f1 ----------------
__global__ __launch_bounds__(256) void k_border(__hip_bfloat16* __restrict__ f1) {
    int t = blockIdx.x * 256 + threadIdx.x;
    const int per_img = 2064;            // 520 + 520 + 1024 uint4 chunks
    if (t >= 32 * per_img) return;
    int b = t / per_img, q = t % per_img;
    int row, px, ch;
    if (q < 520)       { row = 0;   px = q >> 2;         ch = q & 3; }
    else if (q < 1040) { row = 129; px = (q - 520) >> 2; ch = q & 3; }
    else { int z = q - 1040; row = 1 + (z >> 3); int tt = z & 7;
           px = (tt < 4) ? 0 : 129; ch = tt & 3; }
    uint4v zero = {0, 0, 0, 0};
    size_t eo = ((((size_t)b * F1P + row) * F1P + px) * 32 + ch * 8);
    *(uint4v*)((char*)f1 + eo * 2) = zero;
}

// ---------------- conv2 weights -> bf16 [pos][oc][ic] ----------------
__global__ __launch_bounds__(256) void k_prep(const float* __restrict__ w,
        __hip_bfloat16* __restrict__ wt) {
    int t = blockIdx.x * 256 + threadIdx.x;
    if (t >= 18432) return;
    int pos = t / 2048, rem = t % 2048, oc = rem >> 5, ic = rem & 31;
    wt[t] = __float2bfloat16(w[(oc * 32 + ic) * 9 + pos]);
}

// -------- conv2 via MFMA implicit GEMM + maxpool + relu + avgpool -> feat --------
// block = (b, region); region = 32x32 conv px = one 16x16 avgpool block.
__global__ __launch_bounds__(256, 2) void k_conv2m(const __hip_bfloat16* __restrict__ f1,
        const __hip_bfloat16* __restrict__ wt, const float* __restrict__ bias,
        float* __restrict__ feat) {
    __shared__ bf16x8 sbuf[2][1408];     // 2 x 22528 B band buffers
    __shared__ float red[4][64];
    int tid = threadIdx.x;
    int w = tid >> 6, l = tid & 63;
    int lr = l & 15, lg = l >> 4;
    int b = blockIdx.x >> 4, region = blockIdx.x & 15;
    int ry = region >> 2, rx = region & 3;
    const char* f1c = (const char*)(f1 + (size_t)b * F1P * F1P * 32);

    // weight fragments: Bf[n][pos], lane: oc = n*16+lr, ic = lg*8..lg*8+7
    bf16x8 Bf[4][9];
    #pragma unroll
    for (int n = 0; n < 4; ++n)
        #pragma unroll
        for (int p = 0; p < 9; ++p)
            Bf[n][p] = *(const bf16x8*)(wt + ((p * 64 + n * 16 + lr) * 32 + lg * 8));
    float biasv[4];
    #pragma unroll
    for (int n = 0; n < 4; ++n) biasv[n] = bias[n * 16 + lr];

    // staging: 1360 16B elements per band; element i = (r*4+g)*34 + px
    const char* gp[6];
    bool gv[6];
    #pragma unroll
    for (int s = 0; s < 6; ++s) {
        int i = tid + s * 256;
        gv[s] = (i < 1360);
        int ic = gv[s] ? i : 0;
        int r = ic / 136, rem = ic - r * 136, g = rem / 34, px = rem - g * 34;
        int eo = ((ry * 32 + r) * F1P + rx * 32 + px) * 32 + g * 8;
        gp[s] = f1c + (size_t)eo * 2;
    }

    uint4v st[6];
    #pragma unroll
    for (int s = 0; s < 6; ++s) if (gv[s]) st[s] = *(const uint4v*)gp[s];
    #pragma unroll
    for (int s = 0; s < 6; ++s) if (gv[s]) sbuf[0][tid + s * 256] = *(bf16x8*)&st[s];
    __syncthreads();

    float fsum[4] = {0.f, 0.f, 0.f, 0.f};

    for (int band = 0; band < 4; ++band) {
        int d = band & 1;
        if (band < 3) {
            #pragma unroll
            for (int s = 0; s < 6; ++s)
                if (gv[s]) st[s] = *(const uint4v*)(gp[s] + (size_t)(band + 1) * 66560);
        }
        // compute: wave w -> pooled row band*4+w (conv rows band*8+2w, +1)
        #pragma unroll
        for (int xt = 0; xt < 2; ++xt) {
            bf16x8 Af[4][3];
            #pragma unroll
            for (int rr = 0; rr < 4; ++rr)
                #pragma unroll
                for (int dx = 0; dx < 3; ++dx)
                    Af[rr][dx] = sbuf[d][((2 * w + rr) * 4 + lg) * 34 + xt * 16 + lr + dx];
            #pragma unroll
            for (int n = 0; n < 4; ++n) {
                f32x4 a0 = {0.f, 0.f, 0.f, 0.f}, a1 = {0.f, 0.f, 0.f, 0.f};
                #pragma unroll
                for (int dy = 0; dy < 3; ++dy)
                    #pragma unroll
                    for (int dx = 0; dx < 3; ++dx) {
                        a0 = __builtin_amdgcn_mfma_f32_16x16x32_bf16(Af[dy][dx],     Bf[n][dy * 3 + dx], a0, 0, 0, 0);
                        a1 = __builtin_amdgcn_mfma_f32_16x16x32_bf16(Af[dy + 1][dx], Bf[n][dy * 3 + dx], a1, 0, 0, 0);
                    }
                float p0 = fmaxf(fmaxf(a0[0], a0[1]), fmaxf(a1[0], a1[1]));
                float p1 = fmaxf(fmaxf(a0[2], a0[3]), fmaxf(a1[2], a1[3]));
                fsum[n] += fmaxf(p0 + biasv[n], 0.f) + fmaxf(p1 + biasv[n], 0.f);
            }
        }
        __syncthreads();
        if (band < 3) {
            #pragma unroll
            for (int s = 0; s < 6; ++s)
                if (gv[s]) sbuf[d ^ 1][tid + s * 256] = *(bf16x8*)&st[s];
        }
        __syncthreads();
    }

    // reduce: sum over lane groups, then over waves
    #pragma unroll
    for (int n = 0; n < 4; ++n) {
        fsum[n] += __shfl_xor(fsum[n], 16);
        fsum[n] += __shfl_xor(fsum[n], 32);
    }
    if (l < 16) {
        #pragma unroll
        for (int n = 0; n < 4; ++n) red[w][n * 16 + l] = fsum[n];
    }
    __syncthreads();
    if (tid < 64) {
        float s = red[0][tid] + red[1][tid] + red[2][tid] + red[3][tid];
        feat[(size_t)b * 1024 + tid * 16 + region] = s * (1.0f / 256.0f);
    }
}

// ---------------- fc1 (1024->256) + relu ----------------
__global__ __launch_bounds__(256) void k_fc1(const float* __restrict__ feat,
        const float* __restrict__ w, const float* __restrict__ bias,
        float* __restrict__ h) {
    int wave = threadIdx.x >> 6, lane = threadIdx.x & 63;
    int o = blockIdx.x * 4 + wave;
    int b = o >> 8, j = o & 255;
    const float* wr = w + (size_t)j * 1024;
    const float* fb = feat + (size_t)b * 1024;
    float s = 0.f;
    #pragma unroll
    for (int k = lane; k < 1024; k += 64) s = fmaf(wr[k], fb[k], s);
    for (int off = 32; off; off >>= 1) s += __shfl_down(s, off);
    if (lane == 0) h[o] = fmaxf(s + bias[j], 0.f);
}

// ---------------- build and invert the constant 12x12 TPS matrix ----------------
__global__ void k_linv(float* __restrict__ linv) {
    __shared__ float M[12][24];
    if (threadIdx.x == 0) {
        const float cx[9] = {-1,0,1,-1,0,1,-1,0,1};
        const float cy[9] = {-1,-1,-1,0,0,0,1,1,1};
        for (int i = 0; i < 12; ++i)
            for (int j = 0; j < 24; ++j) M[i][j] = 0.f;
        for (int i = 0; i < 9; ++i) {
            for (int j = 0; j < 9; ++j) {
                float dx = cx[i] - cx[j], dy = cy[i] - cy[j];
                float r2 = dx * dx + dy * dy;
                M[i][j] = (r2 > 0.f) ? r2 * logf(r2) : 0.f;
            }
            M[i][9] = 1.f; M[i][10] = cx[i]; M[i][11] = cy[i];
            M[9][i] = 1.f; M[10][i] = cx[i]; M[11][i] = cy[i];
        }
        for (int i = 0; i < 12; ++i) M[i][12 + i] = 1.f;
        for (int c = 0; c < 12; ++c) {
            int p = c;
            for (int r = c + 1; r < 12; ++r)
                if (fabsf(M[r][c]) > fabsf(M[p][c])) p = r;
            if (p != c)
                for (int j = 0; j < 24; ++j) { float t = M[c][j]; M[c][j] = M[p][j]; M[p][j] = t; }
            float inv = 1.f / M[c][c];
            for (int j = 0; j < 24; ++j) M[c][j] *= inv;
            for (int r = 0; r < 12; ++r) if (r != c) {
                float f = M[r][c];
                for (int j = 0; j < 24; ++j) M[r][j] -= f * M[c][j];
            }
        }
        for (int i = 0; i < 12; ++i)
            for (int j = 0; j < 12; ++j) linv[i * 12 + j] = M[i][12 + j];
    }
}

// -------- fc2 (256->18) + Y build + Wfull = Linv @ Y ----------
__global__ __launch_bounds__(64) void k_head(const float* __restrict__ h,
        const float* __restrict__ w2, const float* __restrict__ b2,
        const float* __restrict__ linv, float* __restrict__ wfull) {
    int b = blockIdx.x;
    int t = threadIdx.x;
    __shared__ float Y[12][2];
    __shared__ float L[144];
    const float* hb = h + (size_t)b * 256;
    for (int i = t; i < 144; i += 64) L[i] = linv[i];
    if (t < 18) {
        const float* wr = w2 + (size_t)t * 256;
        float s = 0.f;
        for (int k = 0; k < 256; ++k) s = fmaf(wr[k], hb[k], s);
        s += b2[t];
        int kk = t >> 1, d = t & 1;
        float cp = (d == 0) ? d_cpx[kk] : d_cpy[kk];
        Y[kk][d] = cp + s;
    }
    if (t >= 18 && t < 24) Y[9 + ((t - 18) >> 1)][(t - 18) & 1] = 0.f;
    __syncthreads();
    if (t < 24) {
        int i = t >> 1, d = t & 1;
        float s = 0.f;
        #pragma unroll
        for (int k = 0; k < 12; ++k) s = fmaf(L[i * 12 + k], Y[k][d], s);
        wfull[b * 24 + i * 2 + d] = s;
    }
}

// -------- fused TPS-grid eval + bilinear grid_sample (zero pad) --------
__global__ __launch_bounds__(256) void k_sample(const float* __restrict__ x,
        const float* __restrict__ wfull, float* __restrict__ out) {
    int b = blockIdx.x >> 8;
    int py = blockIdx.x & 255;
    int px = threadIdx.x;
    __shared__ float Wf[24];
    if (threadIdx.x < 24) Wf[threadIdx.x] = wfull[b * 24 + threadIdx.x];
    __syncthreads();
    float gx = px * (2.0f / 255.0f) - 1.0f;
    float gy = py * (2.0f / 255.0f) - 1.0f;
    float sx = Wf[18] + Wf[20] * gx + Wf[22] * gy;
    float sy = Wf[19] + Wf[21] * gx + Wf[23] * gy;
    #pragma unroll
    for (int k = 0; k < 9; ++k) {
        float dx = gx - d_cpx[k], dy = gy - d_cpy[k];
        float r2 = dx * dx + dy * dy;
        float u = (r2 > 0.f) ? r2 * logf(r2) : 0.f;
        sx = fmaf(u, Wf[k * 2 + 0], sx);
        sy = fmaf(u, Wf[k * 2 + 1], sy);
    }
    float xp = (sx + 1.0f) * 0.5f * 255.0f;
    float yp = (sy + 1.0f) * 0.5f * 255.0f;
    float x0f = floorf(xp), y0f = floorf(yp);
    float wx = xp - x0f, wy = yp - y0f;
    int x0 = (int)x0f, y0 = (int)y0f;
    const float* xb = x + (size_t)b * IMG * IMG;
    float v00, v10, v01, v11;
    {
        int ix, iy; bool valid; int ixc, iyc;
        ix = x0;     iy = y0;
        valid = (ix >= 0) && (ix < IMG) && (iy >= 0) && (iy < IMG);
        ixc = min(max(ix, 0), IMG - 1); iyc = min(max(iy, 0), IMG - 1);
        v00 = valid ? xb[iyc * IMG + ixc] : 0.f;
        ix = x0 + 1; iy = y0;
        valid = (ix >= 0) && (ix < IMG) && (iy >= 0) && (iy < IMG);
        ixc = min(max(ix, 0), IMG - 1); iyc = min(max(iy, 0), IMG - 1);
        v10 = valid ? xb[iyc * IMG + ixc] : 0.f;
        ix = x0;     iy = y0 + 1;
        valid = (ix >= 0) && (ix < IMG) && (iy >= 0) && (iy < IMG);
        ixc = min(max(ix, 0), IMG - 1); iyc = min(max(iy, 0), IMG - 1);
        v01 = valid ? xb[iyc * IMG + ixc] : 0.f;
        ix = x0 + 1; iy = y0 + 1;
        valid = (ix >= 0) && (ix < IMG) && (iy >= 0) && (iy < IMG);
        ixc = min(max(ix, 0), IMG - 1); iyc = min(max(iy, 0), IMG - 1);
        v11 = valid ? xb[iyc * IMG + ixc] : 0.f;
    }
    float r = v00 * (1.f - wx) * (1.f - wy) + v10 * wx * (1.f - wy)
            + v01 * (1.f - wx) * wy        + v11 * wx * wy;
    out[(size_t)b * IMG * IMG + py * IMG + px] = r;
}

extern "C" void kernel_launch(void* const* d_in, const int* in_sizes, int n_in,
                              void* d_out, int out_size, void* d_ws, size_t ws_size,
                              hipStream_t stream) {
    const float* x   = (const float*)d_in[0];
    const float* c1w = (const float*)d_in[1];
    const float* c1b = (const float*)d_in[2];
    const float* c2w = (const float*)d_in[3];
    const float* c2b = (const float*)d_in[4];
    const float* w1  = (const float*)d_in[5];
    const float* b1  = (const float*)d_in[6];
    const float* w2  = (const float*)d_in[7];
    const float* b2  = (const float*)d_in[8];
    float* out = (float*)d_out;

    __hip_bfloat16* f1 = (__hip_bfloat16*)d_ws;              // 32*130*130*32 bf16
    __hip_bfloat16* wt = f1 + (size_t)32 * F1P * F1P * 32;   // 18432 bf16
    float* fbase = (float*)(wt + 18432);
    float* feat  = fbase;            // 32*1024
    float* hbuf  = feat + 32768;     // 32*256
    float* wfull = hbuf + 8192;      // 32*24
    float* linv  = wfull + 768;      // 144

    k_linv  <<<1,   64,  0, stream>>>(linv);
    k_prep  <<<72,  256, 0, stream>>>(c2w, wt);
    k_border<<<259, 256, 0, stream>>>(f1);
    k_conv1 <<<BATCH * 64, 256, 0, stream>>>(x, c1w, c1b, f1);
    k_conv2m<<<BATCH * 16, 256, 0, stream>>>(f1, wt, c2b, feat);
    k_fc1   <<<2048, 256, 0, stream>>>(feat, w1, b1, hbuf);
    k_head  <<<BATCH, 64, 0, stream>>>(hbuf, w2, b2, linv, wfull);
    k_sample<<<BATCH * 256, 256, 0, stream>>>(x, wfull, out);
}

// Round 3
// 94.575 us; speedup vs baseline: 4.8894x; 1.4708x over previous
//
#include <hip/hip_runtime.h>
#include <hip/hip_bf16.h>
#include <math.h>

#define BATCH 32
#define IMG 256
#define NCP 9
#define F1P 130              // padded spatial dim of f1 (128 + 2 border)

typedef __attribute__((ext_vector_type(8))) short bf16x8;
typedef __attribute__((ext_vector_type(4))) float f32x4;
typedef __attribute__((ext_vector_type(4))) unsigned int uint4v;

__device__ __constant__ float d_cpx[9] = {-1.f,0.f,1.f,-1.f,0.f,1.f,-1.f,0.f,1.f};
__device__ __constant__ float d_cpy[9] = {-1.f,-1.f,-1.f,0.f,0.f,0.f,1.f,1.f,1.f};

__device__ inline unsigned int pack2bf(float a, float b) {
    __hip_bfloat16 ha = __float2bfloat16(a), hb = __float2bfloat16(b);
    unsigned short ua = *(unsigned short*)&ha, ub = *(unsigned short*)&hb;
    return ((unsigned int)ub << 16) | ua;
}

// ---- prep: block0 = wave-parallel GJ inverse of the constant 12x12 L;
//      blocks 1.. : conv2 weight transpose->bf16 and f1 border zeroing ----
__global__ __launch_bounds__(256) void k_prep(const float* __restrict__ w,
        __hip_bfloat16* __restrict__ wt, __hip_bfloat16* __restrict__ f1,
        float* __restrict__ linv) {
    int blk = blockIdx.x;
    if (blk == 0) {
        int j = threadIdx.x;
        if (j >= 24) return;
        const float cx[9] = {-1,0,1,-1,0,1,-1,0,1};
        const float cy[9] = {-1,-1,-1,0,0,0,1,1,1};
        float col[12];
        #pragma unroll
        for (int i = 0; i < 12; ++i) {
            float v;
            if (j < 12) {
                if (i < 9 && j < 9) {
                    float dx = cx[i] - cx[j], dy = cy[i] - cy[j];
                    float r2 = dx * dx + dy * dy;
                    v = (r2 > 0.f) ? r2 * logf(r2) : 0.f;
                } else if (i < 9) {
                    v = (j == 9) ? 1.f : ((j == 10) ? cx[i] : cy[i]);
                } else if (j < 9) {
                    v = (i == 9) ? 1.f : ((i == 10) ? cx[j] : cy[j]);
                } else v = 0.f;
            } else v = (i == j - 12) ? 1.f : 0.f;
            col[i] = v;
        }
        #pragma unroll
        for (int c = 0; c < 12; ++c) {
            float f[12];
            #pragma unroll
            for (int i = 0; i < 12; ++i) f[i] = __shfl(col[i], c);
            int p = c; float best = fabsf(f[c]);
            #pragma unroll
            for (int r = 0; r < 12; ++r) if (r > c) {
                float a = fabsf(f[r]);
                bool g = a > best;
                best = g ? a : best;
                p = g ? r : p;
            }
            float oldc = col[c], colp = col[c];
            #pragma unroll
            for (int r = 0; r < 12; ++r) colp = (r == p) ? col[r] : colp;
            #pragma unroll
            for (int r = 0; r < 12; ++r) col[r] = (r == p) ? oldc : col[r];
            col[c] = colp;
            float oldfc = f[c], fpv = f[c];
            #pragma unroll
            for (int r = 0; r < 12; ++r) fpv = (r == p) ? f[r] : fpv;
            #pragma unroll
            for (int r = 0; r < 12; ++r) f[r] = (r == p) ? oldfc : f[r];
            f[c] = fpv;
            float inv = 1.0f / f[c];
            col[c] *= inv;
            #pragma unroll
            for (int r = 0; r < 12; ++r) if (r != c) col[r] = fmaf(-f[r], col[c], col[r]);
        }
        if (j >= 12) {
            #pragma unroll
            for (int i = 0; i < 12; ++i) linv[i * 12 + (j - 12)] = col[i];
        }
        return;
    }
    int t = (blk - 1) * 256 + threadIdx.x;
    if (t < 18432) {
        int pos = t / 2048, rem = t % 2048, oc = rem >> 5, ic = rem & 31;
        wt[t] = __float2bfloat16(w[(oc * 32 + ic) * 9 + pos]);
        return;
    }
    int u = t - 18432;
    if (u < 32 * 2064) {
        int b = u / 2064, q = u % 2064;
        int row, px, ch;
        if (q < 520)       { row = 0;   px = q >> 2;         ch = q & 3; }
        else if (q < 1040) { row = 129; px = (q - 520) >> 2; ch = q & 3; }
        else { int z = q - 1040; row = 1 + (z >> 3); int tt = z & 7;
               px = (tt < 4) ? 0 : 129; ch = tt & 3; }
        uint4v zero = {0, 0, 0, 0};
        size_t eo = ((((size_t)b * F1P + row) * F1P + px) * 32 + ch * 8);
        *(uint4v*)((char*)f1 + eo * 2) = zero;
    }
}

// ---------------- conv1 (1->32) + maxpool2 + relu -> f1 [b][y+1][x+1][ic] bf16 ----
__global__ __launch_bounds__(256) void k_conv1(const float* __restrict__ x,
        const float* __restrict__ w, const float* __restrict__ bias,
        __hip_bfloat16* __restrict__ f1) {
    int blk = blockIdx.x;
    int tj = blk & 7, ti = (blk >> 3) & 7, b = blk >> 6;
    __shared__ float tile[34 * 34];
    __shared__ float wl[32 * 9];
    __shared__ float bl[32];
    int tid = threadIdx.x;
    for (int i = tid; i < 32 * 9; i += 256) wl[i] = w[i];
    if (tid < 32) bl[tid] = bias[tid];
    const float* xb = x + (size_t)b * IMG * IMG;
    int oy0 = ti * 32 - 1, ox0 = tj * 32 - 1;
    for (int i = tid; i < 34 * 34; i += 256) {
        int yy = i / 34, xx = i % 34;
        int r = oy0 + yy, c = ox0 + xx;
        float v = 0.f;
        if (r >= 0 && r < IMG && c >= 0 && c < IMG) v = xb[r * IMG + c];
        tile[i] = v;
    }
    __syncthreads();
    int oy = tid >> 4, ox = tid & 15;
    float p[16];
    #pragma unroll
    for (int yy = 0; yy < 4; ++yy)
        #pragma unroll
        for (int xx = 0; xx < 4; ++xx)
            p[yy * 4 + xx] = tile[(2 * oy + yy) * 34 + (2 * ox + xx)];
    int gy = ti * 16 + oy, gx = tj * 16 + ox;
    unsigned int u[16];
    #pragma unroll
    for (int oc2 = 0; oc2 < 16; ++oc2) {
        float vv[2];
        #pragma unroll
        for (int h = 0; h < 2; ++h) {
            int oc = oc2 * 2 + h;
            float ww[9];
            #pragma unroll
            for (int k = 0; k < 9; ++k) ww[k] = wl[oc * 9 + k];
            float m = -INFINITY;
            #pragma unroll
            for (int dy = 0; dy < 2; ++dy)
                #pragma unroll
                for (int dx = 0; dx < 2; ++dx) {
                    float s = 0.f;
                    #pragma unroll
                    for (int ky = 0; ky < 3; ++ky)
                        #pragma unroll
                        for (int kx = 0; kx < 3; ++kx)
                            s = fmaf(p[(dy + ky) * 4 + dx + kx], ww[ky * 3 + kx], s);
                    m = fmaxf(m, s);
                }
            vv[h] = fmaxf(m + bl[oc], 0.f);
        }
        u[oc2] = pack2bf(vv[0], vv[1]);
    }
    size_t eo = (((size_t)b * F1P + (gy + 1)) * F1P + (gx + 1)) * 32;
    uint4v* dst = (uint4v*)((char*)f1 + eo * 2);
    #pragma unroll
    for (int q = 0; q < 4; ++q) {
        uint4v vq = { u[q*4+0], u[q*4+1], u[q*4+2], u[q*4+3] };
        dst[q] = vq;
    }
}

// -------- conv2 via direct-load MFMA implicit GEMM + maxpool + relu + avgpool --------
// block = (b, region, ochalf); region = 32x32 conv px = one 16x16 avgpool block.
// No LDS staging: A-fragments are aligned 16B global loads (L1/L2-served).
__global__ __launch_bounds__(256, 3) void k_conv2m(const __hip_bfloat16* __restrict__ f1,
        const __hip_bfloat16* __restrict__ wt, const float* __restrict__ bias,
        float* __restrict__ feat) {
    __shared__ float red[4][32];
    int tid = threadIdx.x;
    int w = tid >> 6, l = tid & 63;
    int lr = l & 15, lg = l >> 4;
    int blk = blockIdx.x;
    int oh = blk & 1;
    int region = (blk >> 1) & 15;
    int b = blk >> 5;
    int ry = region >> 2, rx = region & 3;
    const __hip_bfloat16* f1b = f1 + (size_t)b * F1P * F1P * 32;

    // weight fragments: lane holds oc = oh*32 + n*16 + lr, ic = lg*8..lg*8+7
    bf16x8 Bf[2][9];
    #pragma unroll
    for (int n = 0; n < 2; ++n)
        #pragma unroll
        for (int p = 0; p < 9; ++p)
            Bf[n][p] = *(const bf16x8*)(wt + ((size_t)(p * 64 + oh * 32 + n * 16 + lr) * 32 + lg * 8));
    float biasv[2];
    #pragma unroll
    for (int n = 0; n < 2; ++n) biasv[n] = bias[oh * 32 + n * 16 + lr];

    float fsum[2] = {0.f, 0.f};

    #pragma unroll 1
    for (int b4 = 0; b4 < 4; ++b4) {
        int pr = b4 * 4 + w;                   // pooled row 0..15 in region
        int row0 = ry * 32 + 2 * pr;           // padded f1 row base
        #pragma unroll
        for (int xt = 0; xt < 2; ++xt) {
            int x0 = rx * 32 + xt * 16 + lr;   // padded x
            bf16x8 Af[4][3];
            #pragma unroll
            for (int rr = 0; rr < 4; ++rr)
                #pragma unroll
                for (int dx = 0; dx < 3; ++dx)
                    Af[rr][dx] = *(const bf16x8*)(f1b + ((size_t)(row0 + rr) * F1P + x0 + dx) * 32 + lg * 8);
            #pragma unroll
            for (int n = 0; n < 2; ++n) {
                f32x4 a0 = {0.f, 0.f, 0.f, 0.f}, a1 = {0.f, 0.f, 0.f, 0.f};
                #pragma unroll
                for (int dy = 0; dy < 3; ++dy)
                    #pragma unroll
                    for (int dx = 0; dx < 3; ++dx) {
                        a0 = __builtin_amdgcn_mfma_f32_16x16x32_bf16(Af[dy][dx],     Bf[n][dy * 3 + dx], a0, 0, 0, 0);
                        a1 = __builtin_amdgcn_mfma_f32_16x16x32_bf16(Af[dy + 1][dx], Bf[n][dy * 3 + dx], a1, 0, 0, 0);
                    }
                float p0 = fmaxf(fmaxf(a0[0], a0[1]), fmaxf(a1[0], a1[1]));
                float p1 = fmaxf(fmaxf(a0[2], a0[3]), fmaxf(a1[2], a1[3]));
                fsum[n] += fmaxf(p0 + biasv[n], 0.f) + fmaxf(p1 + biasv[n], 0.f);
            }
        }
    }

    #pragma unroll
    for (int n = 0; n < 2; ++n) {
        fsum[n] += __shfl_xor(fsum[n], 16);
        fsum[n] += __shfl_xor(fsum[n], 32);
    }
    if (l < 16) {
        red[w][0 * 16 + l] = fsum[0];
        red[w][1 * 16 + l] = fsum[1];
    }
    __syncthreads();
    if (tid < 32) {
        float s = red[0][tid] + red[1][tid] + red[2][tid] + red[3][tid];
        feat[(size_t)b * 1024 + (oh * 32 + tid) * 16 + region] = s * (1.0f / 256.0f);
    }
}

// ---------------- fc1 (1024->256) + relu ----------------
__global__ __launch_bounds__(256) void k_fc1(const float* __restrict__ feat,
        const float* __restrict__ w, const float* __restrict__ bias,
        float* __restrict__ h) {
    int wave = threadIdx.x >> 6, lane = threadIdx.x & 63;
    int o = blockIdx.x * 4 + wave;
    int b = o >> 8, j = o & 255;
    const float* wr = w + (size_t)j * 1024;
    const float* fb = feat + (size_t)b * 1024;
    float s = 0.f;
    #pragma unroll
    for (int k = lane; k < 1024; k += 64) s = fmaf(wr[k], fb[k], s);
    for (int off = 32; off; off >>= 1) s += __shfl_down(s, off);
    if (lane == 0) h[o] = fmaxf(s + bias[j], 0.f);
}

// -------- fc2 (256->18) + Y build + Wfull = Linv @ Y ----------
__global__ __launch_bounds__(64) void k_head(const float* __restrict__ h,
        const float* __restrict__ w2, const float* __restrict__ b2,
        const float* __restrict__ linv, float* __restrict__ wfull) {
    int b = blockIdx.x;
    int t = threadIdx.x;
    __shared__ float Y[12][2];
    __shared__ float L[144];
    const float* hb = h + (size_t)b * 256;
    for (int i = t; i < 144; i += 64) L[i] = linv[i];
    if (t < 18) {
        const float* wr = w2 + (size_t)t * 256;
        float s = 0.f;
        for (int k = 0; k < 256; ++k) s = fmaf(wr[k], hb[k], s);
        s += b2[t];
        int kk = t >> 1, d = t & 1;
        float cp = (d == 0) ? d_cpx[kk] : d_cpy[kk];
        Y[kk][d] = cp + s;
    }
    if (t >= 18 && t < 24) Y[9 + ((t - 18) >> 1)][(t - 18) & 1] = 0.f;
    __syncthreads();
    if (t < 24) {
        int i = t >> 1, d = t & 1;
        float s = 0.f;
        #pragma unroll
        for (int k = 0; k < 12; ++k) s = fmaf(L[i * 12 + k], Y[k][d], s);
        wfull[b * 24 + i * 2 + d] = s;
    }
}

// -------- fused TPS-grid eval + bilinear grid_sample (zero pad) --------
__global__ __launch_bounds__(256) void k_sample(const float* __restrict__ x,
        const float* __restrict__ wfull, float* __restrict__ out) {
    int b = blockIdx.x >> 8;
    int py = blockIdx.x & 255;
    int px = threadIdx.x;
    __shared__ float Wf[24];
    if (threadIdx.x < 24) Wf[threadIdx.x] = wfull[b * 24 + threadIdx.x];
    __syncthreads();
    float gx = px * (2.0f / 255.0f) - 1.0f;
    float gy = py * (2.0f / 255.0f) - 1.0f;
    float sx = Wf[18] + Wf[20] * gx + Wf[22] * gy;
    float sy = Wf[19] + Wf[21] * gx + Wf[23] * gy;
    #pragma unroll
    for (int k = 0; k < 9; ++k) {
        float dx = gx - d_cpx[k], dy = gy - d_cpy[k];
        float r2 = dx * dx + dy * dy;
        float u = (r2 > 0.f) ? r2 * logf(r2) : 0.f;
        sx = fmaf(u, Wf[k * 2 + 0], sx);
        sy = fmaf(u, Wf[k * 2 + 1], sy);
    }
    float xp = (sx + 1.0f) * 0.5f * 255.0f;
    float yp = (sy + 1.0f) * 0.5f * 255.0f;
    float x0f = floorf(xp), y0f = floorf(yp);
    float wx = xp - x0f, wy = yp - y0f;
    int x0 = (int)x0f, y0 = (int)y0f;
    const float* xb = x + (size_t)b * IMG * IMG;
    float v00, v10, v01, v11;
    {
        int ix, iy; bool valid; int ixc, iyc;
        ix = x0;     iy = y0;
        valid = (ix >= 0) && (ix < IMG) && (iy >= 0) && (iy < IMG);
        ixc = min(max(ix, 0), IMG - 1); iyc = min(max(iy, 0), IMG - 1);
        v00 = valid ? xb[iyc * IMG + ixc] : 0.f;
        ix = x0 + 1; iy = y0;
        valid = (ix >= 0) && (ix < IMG) && (iy >= 0) && (iy < IMG);
        ixc = min(max(ix, 0), IMG - 1); iyc = min(max(iy, 0), IMG - 1);
        v10 = valid ? xb[iyc * IMG + ixc] : 0.f;
        ix = x0;     iy = y0 + 1;
        valid = (ix >= 0) && (ix < IMG) && (iy >= 0) && (iy < IMG);
        ixc = min(max(ix, 0), IMG - 1); iyc = min(max(iy, 0), IMG - 1);
        v01 = valid ? xb[iyc * IMG + ixc] : 0.f;
        ix = x0 + 1; iy = y0 + 1;
        valid = (ix >= 0) && (ix < IMG) && (iy >= 0) && (iy < IMG);
        ixc = min(max(ix, 0), IMG - 1); iyc = min(max(iy, 0), IMG - 1);
        v11 = valid ? xb[iyc * IMG + ixc] : 0.f;
    }
    float r = v00 * (1.f - wx) * (1.f - wy) + v10 * wx * (1.f - wy)
            + v01 * (1.f - wx) * wy        + v11 * wx * wy;
    out[(size_t)b * IMG * IMG + py * IMG + px] = r;
}

extern "C" void kernel_launch(void* const* d_in, const int* in_sizes, int n_in,
                              void* d_out, int out_size, void* d_ws, size_t ws_size,
                              hipStream_t stream) {
    const float* x   = (const float*)d_in[0];
    const float* c1w = (const float*)d_in[1];
    const float* c1b = (const float*)d_in[2];
    const float* c2w = (const float*)d_in[3];
    const float* c2b = (const float*)d_in[4];
    const float* w1  = (const float*)d_in[5];
    const float* b1  = (const float*)d_in[6];
    const float* w2  = (const float*)d_in[7];
    const float* b2  = (const float*)d_in[8];
    float* out = (float*)d_out;

    __hip_bfloat16* f1 = (__hip_bfloat16*)d_ws;              // 32*130*130*32 bf16
    __hip_bfloat16* wt = f1 + (size_t)32 * F1P * F1P * 32;   // 18432 bf16
    float* fbase = (float*)(wt + 18432);
    float* feat  = fbase;            // 32*1024
    float* hbuf  = feat + 32768;     // 32*256
    float* wfull = hbuf + 8192;      // 32*24
    float* linv  = wfull + 768;      // 144

    k_prep  <<<331, 256, 0, stream>>>(c2w, wt, f1, linv);
    k_conv1 <<<BATCH * 64, 256, 0, stream>>>(x, c1w, c1b, f1);
    k_conv2m<<<BATCH * 32, 256, 0, stream>>>(f1, wt, c2b, feat);
    k_fc1   <<<2048, 256, 0, stream>>>(feat, w1, b1, hbuf);
    k_head  <<<BATCH, 64, 0, stream>>>(hbuf, w2, b2, linv, wfull);
    k_sample<<<BATCH * 256, 256, 0, stream>>>(x, wfull, out);
}